// Round 4
// baseline (19905.525 us; speedup 1.0000x reference)
//
#include <hip/hip_runtime.h>
#include <hip/hip_bf16.h>

typedef __attribute__((ext_vector_type(8))) short short8;
typedef __attribute__((ext_vector_type(4))) float f32x4;

#define T_STEPS 512
#define BATCH   256
#define HDIM    1024
#define GDIM    4096   // 4*H

__device__ __forceinline__ float sigmoidf_(float x) {
  return 1.0f / (1.0f + __expf(-x));
}
__device__ __forceinline__ float tanh_(float x) {
  return 2.0f / (1.0f + __expf(-2.0f * x)) - 1.0f;
}
__device__ __forceinline__ short f2bf(float f) {
  __hip_bfloat16 h = __float2bfloat16(f);
  short s;
  __builtin_memcpy(&s, &h, sizeof(short));
  return s;
}

// ---------------------------------------------------------------------------
// Split grid barrier (8 XCD-groups x 32 blocks). Called by tid 0 only,
// after __syncthreads() has drained the block's stores.
// ---------------------------------------------------------------------------
__device__ __forceinline__ unsigned bar_arrive(unsigned* bar, int grp) {
  __threadfence();   // release: write back this XCD's dirty L2
  unsigned* gcnt = bar + (size_t)grp * 32;
  unsigned* gctr = bar + 8 * 32;
  unsigned* gen  = bar + 8 * 32 + 32;
  unsigned g = __hip_atomic_load(gen, __ATOMIC_RELAXED, __HIP_MEMORY_SCOPE_AGENT);
  unsigned a = __hip_atomic_fetch_add(gcnt, 1u, __ATOMIC_ACQ_REL, __HIP_MEMORY_SCOPE_AGENT);
  if (a == 31u) {
    __hip_atomic_store(gcnt, 0u, __ATOMIC_RELAXED, __HIP_MEMORY_SCOPE_AGENT);
    unsigned ga = __hip_atomic_fetch_add(gctr, 1u, __ATOMIC_ACQ_REL, __HIP_MEMORY_SCOPE_AGENT);
    if (ga == 7u) {
      __hip_atomic_store(gctr, 0u, __ATOMIC_RELAXED, __HIP_MEMORY_SCOPE_AGENT);
      __hip_atomic_store(gen, g + 1u, __ATOMIC_RELEASE, __HIP_MEMORY_SCOPE_AGENT);
    }
  }
  return g;
}
__device__ __forceinline__ void bar_wait(unsigned* bar, unsigned g) {
  unsigned* gen = bar + 8 * 32 + 32;
  while (__hip_atomic_load(gen, __ATOMIC_RELAXED, __HIP_MEMORY_SCOPE_AGENT) == g)
    __builtin_amdgcn_s_sleep(2);
  __threadfence();   // acquire: invalidate stale L1/L2
}

// ---------------------------------------------------------------------------
// Pack: Whb=bf16(Wh), Wxb=bf16(Wx) [4096][1024]; biasc = bx + bh
// ---------------------------------------------------------------------------
__global__ void pack_kernel(const float* __restrict__ Wh, const float* __restrict__ Wx,
                            const float* __restrict__ bx, const float* __restrict__ bh,
                            __hip_bfloat16* __restrict__ Whb,
                            __hip_bfloat16* __restrict__ Wxb,
                            float* __restrict__ biasc)
{
  const int stride = gridDim.x * blockDim.x;
  const int tid0 = blockIdx.x * blockDim.x + threadIdx.x;
  for (int i = tid0; i < GDIM * HDIM; i += stride) {
    Whb[i] = __float2bfloat16(Wh[i]);
    Wxb[i] = __float2bfloat16(Wx[i]);
  }
  for (int i = tid0; i < GDIM; i += stride)
    biasc[i] = bx[i] + bh[i];
}

// ---------------------------------------------------------------------------
// Persistent LSTM: ALL 512 steps in one cooperative launch.
// 256 blocks (1/CU) x 512 thr (8 waves: rf 0..3 x kh 0..1).
// Block tile: 64 batch x (16 j-cols x 4 gates). Wh slice resident in LDS.
// Per step: phase A = recurrence GEMM (K=1024, A-frags loaded direct from
// global h, B from LDS) + fused peephole cell; phase B = produce next step's
// xg tile IN REGISTERS (x fp32 frags + Wxb frags direct from global),
// overlapping the grid-barrier wait.
// ---------------------------------------------------------------------------
__global__ __launch_bounds__(512, 1)
void lstm_persist(const float* __restrict__ x,
                  const __hip_bfloat16* __restrict__ Whb,
                  const __hip_bfloat16* __restrict__ Wxb,
                  const float* __restrict__ biasc,
                  const float* __restrict__ c2c,
                  __hip_bfloat16* __restrict__ hb0,
                  __hip_bfloat16* __restrict__ hb1,
                  unsigned* __restrict__ bar)
{
  __shared__ short8 Bp[8192];   // 128 KB: Wh slice, 64 gate-rows x 1024 k
  __shared__ float  red[4096];  // 16 KB: k-half reduction (64x64)

  const int tid  = threadIdx.x;
  const int wave = tid >> 6;
  const int lane = tid & 63;

  // XCD-paired mapping: blocks sharing a batch-slice (mtile) live on an XCD
  // pair -> their x/h reads stay in 2 L2s.
  const int bid   = blockIdx.x;
  const int xcd   = bid & 7;
  const int mtile = xcd >> 1;                      // 0..3
  const int ntile = (xcd & 1) * 32 + (bid >> 3);   // 0..63
  const int b0 = mtile * 64;
  const int j0 = ntile * 16;

  // ---- fill persistent Wh slice ----
  for (int i = tid; i < 8192; i += 512) {
    const int row = i >> 7, ck = i & 127;
    const int grow = (row >> 4) * HDIM + j0 + (row & 15);
    Bp[row * 128 + (ck ^ (row & 7))] =
        *(const short8*)(const void*)(Whb + (size_t)grow * HDIM + ck * 8);
  }

  // ---- geometry ----
  const int rf  = wave & 3;    // 16-row batch fragment
  const int kh  = wave >> 2;   // k-half
  const int l15 = lane & 15;
  const int lg  = lane >> 4;                 // 0..3
  const int arow_g = b0 + rf * 16 + l15;     // global batch row for A-frags
  const int kbase  = kh * 32 + lg * 8;       // k offset within a 64-k chunk

  int bbase[4];
#pragma unroll
  for (int f = 0; f < 4; ++f) {
    const int br = f * 16 + l15;
    bbase[f] = br * 128 + ((kh * 4 + lg) ^ (br & 7));
  }

  // phase-B sources
  const float* xrow = x + (size_t)arow_g * T_STEPS * 1024;
  const __hip_bfloat16* wxr[4];
#pragma unroll
  for (int f = 0; f < 4; ++f)
    wxr[f] = Wxb + (size_t)(f * 1024 + j0 + l15) * 1024 + kbase;

  // ---- epilogue constants ----
  const int dcol = l15;
  const int drow = lg * 4;
  const int jj = j0 + dcol;
  const float bi  = biasc[jj];
  const float bfv = biasc[HDIM + jj];
  const float bg  = biasc[2 * HDIM + jj];
  const float bo  = biasc[3 * HDIM + jj];
  const float ci  = c2c[jj];
  const float cf  = c2c[HDIM + jj];
  const float co  = c2c[2 * HDIM + jj];
  const int eb0 = b0 + rf * 16 + drow;

  float c_reg[4] = {0.f, 0.f, 0.f, 0.f};
  f32x4 xgr[4];
#pragma unroll
  for (int f = 0; f < 4; ++f) xgr[f] = (f32x4){0.f, 0.f, 0.f, 0.f};

  __syncthreads();   // Bp ready

  // ---- phase B: produce xg(T) into xgr (register-resident) ----
#define PHASE_B(T)                                                            \
  do {                                                                        \
    f32x4 accx[4];                                                            \
    _Pragma("unroll")                                                         \
    for (int f = 0; f < 4; ++f) accx[f] = (f32x4){0.f, 0.f, 0.f, 0.f};        \
    const float* xp = xrow + (size_t)(T) * 1024 + kbase;                      \
    f32x4 xl[2], xh[2]; short8 bxf[2][4];                                     \
    xl[0] = *(const f32x4*)(xp);                                              \
    xh[0] = *(const f32x4*)(xp + 4);                                          \
    _Pragma("unroll")                                                         \
    for (int f = 0; f < 4; ++f)                                               \
      bxf[0][f] = *(const short8*)(const void*)(wxr[f]);                      \
    _Pragma("unroll")                                                         \
    for (int kc = 0; kc < 16; ++kc) {                                         \
      const int cur = kc & 1, nxt = cur ^ 1;                                  \
      if (kc < 15) {                                                          \
        xl[nxt] = *(const f32x4*)(xp + (kc + 1) * 64);                        \
        xh[nxt] = *(const f32x4*)(xp + (kc + 1) * 64 + 4);                    \
        _Pragma("unroll")                                                     \
        for (int f = 0; f < 4; ++f)                                           \
          bxf[nxt][f] = *(const short8*)(const void*)(wxr[f] + (kc + 1) * 64);\
      }                                                                       \
      short8 xa;                                                              \
      _Pragma("unroll")                                                       \
      for (int e = 0; e < 4; ++e) {                                           \
        xa[e] = f2bf(xl[cur][e]); xa[e + 4] = f2bf(xh[cur][e]);               \
      }                                                                       \
      _Pragma("unroll")                                                       \
      for (int f = 0; f < 4; ++f)                                             \
        accx[f] = __builtin_amdgcn_mfma_f32_16x16x32_bf16(xa, bxf[cur][f],    \
                                                          accx[f], 0, 0, 0); \
    }                                                                         \
    __syncthreads();                                                          \
    if (kh == 1) {                                                            \
      _Pragma("unroll")                                                       \
      for (int f = 0; f < 4; ++f)                                             \
        _Pragma("unroll")                                                     \
        for (int r = 0; r < 4; ++r)                                           \
          red[(rf * 16 + drow + r) * 64 + f * 16 + dcol] = accx[f][r];        \
    }                                                                         \
    __syncthreads();                                                          \
    if (kh == 0) {                                                            \
      _Pragma("unroll")                                                       \
      for (int f = 0; f < 4; ++f)                                             \
        _Pragma("unroll")                                                     \
        for (int r = 0; r < 4; ++r)                                           \
          xgr[f][r] = accx[f][r] +                                            \
                      red[(rf * 16 + drow + r) * 64 + f * 16 + dcol];         \
    }                                                                         \
  } while (0)

  PHASE_B(0);   // prologue: xg for step 0
  __syncthreads();

#pragma unroll 1
  for (int s = 0; s < T_STEPS; ++s) {
    const __hip_bfloat16* hin = (s & 1) ? hb1 : hb0;
    __hip_bfloat16* hout      = (s & 1) ? hb0 : hb1;

    // ---- phase A: recurrence GEMM, A-frags direct from global h ----
    const __hip_bfloat16* hp = hin + (size_t)arow_g * HDIM + kbase;
    short8 hv[16];
#pragma unroll
    for (int kc = 0; kc < 16; ++kc)
      hv[kc] = *(const short8*)(const void*)(hp + kc * 64);

    f32x4 acc[4];
#pragma unroll
    for (int f = 0; f < 4; ++f) acc[f] = (f32x4){0.f, 0.f, 0.f, 0.f};

#pragma unroll
    for (int kc = 0; kc < 16; ++kc) {
#pragma unroll
      for (int f = 0; f < 4; ++f)
        acc[f] = __builtin_amdgcn_mfma_f32_16x16x32_bf16(hv[kc], Bp[bbase[f] + kc * 8],
                                                         acc[f], 0, 0, 0);
    }

    __syncthreads();
    if (kh == 1) {
#pragma unroll
      for (int f = 0; f < 4; ++f)
#pragma unroll
        for (int r = 0; r < 4; ++r)
          red[(rf * 16 + drow + r) * 64 + f * 16 + dcol] = acc[f][r];
    }
    __syncthreads();
    if (kh == 0) {
#pragma unroll
      for (int r = 0; r < 4; ++r) {
        const int rr = (rf * 16 + drow + r) * 64 + dcol;
        float gI = acc[0][r] + red[rr +  0] + xgr[0][r] + bi;
        float gF = acc[1][r] + red[rr + 16] + xgr[1][r] + bfv;
        float gG = acc[2][r] + red[rr + 32] + xgr[2][r] + bg;
        float gO = acc[3][r] + red[rr + 48] + xgr[3][r] + bo;
        float cp = c_reg[r];
        float ig = sigmoidf_(gI + ci * cp);
        float fg = sigmoidf_(gF + cf * cp);
        float gg = tanh_(gG);
        float cn = fg * cp + ig * gg;
        float og = sigmoidf_(gO + co * cn);
        c_reg[r] = cn;
        hout[(size_t)(eb0 + r) * HDIM + jj] = __float2bfloat16(og * tanh_(cn));
      }
    }
    if (s == T_STEPS - 1) break;

    __syncthreads();   // h stores drained (vmcnt 0), red reads done
    unsigned g = 0;
    if (tid == 0) g = bar_arrive(bar, xcd);   // release h(s+1)

    PHASE_B(s + 1);    // overlaps barrier latency (independent of h)

    if (tid == 0) bar_wait(bar, g);
    __syncthreads();
  }
#undef PHASE_B
}

// ---------------------------------------------------------------------------
// Final FC: out[b][o] = h[b][:] . Wfc[o][:] + bfc[o]  (M=256,N=1024,K=1024)
// ---------------------------------------------------------------------------
__global__ __launch_bounds__(256, 1)
void fc_kernel(const __hip_bfloat16* __restrict__ h,
               const float* __restrict__ Wfc,
               const float* __restrict__ bfc,
               float* __restrict__ out)
{
  __shared__ short8 As8[512];
  __shared__ short8 Bs8[512];

  const int tid = threadIdx.x;
  const int wave = tid >> 6;
  const int lane = tid & 63;
  const int mtile = blockIdx.x >> 4;
  const int otile = blockIdx.x & 15;
  const int b0 = mtile * 64, o0 = otile * 64;

  const int r0 = tid >> 3;
  const int cg0 = tid & 7;

  f32x4 acc[4];
#pragma unroll
  for (int f = 0; f < 4; ++f) acc[f] = (f32x4){0.f, 0.f, 0.f, 0.f};

#pragma unroll 1
  for (int kc = 0; kc < 16; ++kc) {
    __syncthreads();
    As8[r0 * 8 + (cg0 ^ (r0 & 7))] =
        *(const short8*)(const void*)(h + (size_t)(b0 + r0) * HDIM + kc * 64 + cg0 * 8);
    As8[(r0 + 32) * 8 + (cg0 ^ (r0 & 7))] =
        *(const short8*)(const void*)(h + (size_t)(b0 + r0 + 32) * HDIM + kc * 64 + cg0 * 8);
    {
      const float* p0 = Wfc + (size_t)(o0 + r0) * HDIM + kc * 64 + cg0 * 8;
      const float* p1 = Wfc + (size_t)(o0 + r0 + 32) * HDIM + kc * 64 + cg0 * 8;
      f32x4 l0 = *(const f32x4*)p0, h0 = *(const f32x4*)(p0 + 4);
      f32x4 l1 = *(const f32x4*)p1, h1 = *(const f32x4*)(p1 + 4);
      short8 s0, s1;
#pragma unroll
      for (int e = 0; e < 4; ++e) {
        s0[e] = f2bf(l0[e]); s0[e + 4] = f2bf(h0[e]);
        s1[e] = f2bf(l1[e]); s1[e + 4] = f2bf(h1[e]);
      }
      Bs8[r0 * 8 + (cg0 ^ (r0 & 7))] = s0;
      Bs8[(r0 + 32) * 8 + (cg0 ^ (r0 & 7))] = s1;
    }
    __syncthreads();
#pragma unroll
    for (int s = 0; s < 2; ++s) {
      const int colg = s * 4 + (lane >> 4);
      const int ar = wave * 16 + (lane & 15);
      short8 af = As8[ar * 8 + (colg ^ (ar & 7))];
#pragma unroll
      for (int f = 0; f < 4; ++f) {
        const int br = f * 16 + (lane & 15);
        short8 bfq = Bs8[br * 8 + (colg ^ (br & 7))];
        acc[f] = __builtin_amdgcn_mfma_f32_16x16x32_bf16(af, bfq, acc[f], 0, 0, 0);
      }
    }
  }

  const int dcol = lane & 15;
  const int drow = (lane >> 4) * 4;
#pragma unroll
  for (int f = 0; f < 4; ++f) {
    const int o = o0 + f * 16 + dcol;
    const float bias = bfc[o];
#pragma unroll
    for (int r = 0; r < 4; ++r) {
      const int b = b0 + wave * 16 + drow + r;
      out[(size_t)b * 1024 + o] = acc[f][r] + bias;
    }
  }
}

// ---------------------------------------------------------------------------
extern "C" void kernel_launch(void* const* d_in, const int* in_sizes, int n_in,
                              void* d_out, int out_size, void* d_ws, size_t ws_size,
                              hipStream_t stream)
{
  const float* x   = (const float*)d_in[0];
  const float* Wx  = (const float*)d_in[1];
  const float* bx  = (const float*)d_in[2];
  const float* Wh  = (const float*)d_in[3];
  const float* bh  = (const float*)d_in[4];
  const float* c2c = (const float*)d_in[5];
  const float* Wfc = (const float*)d_in[6];
  const float* bfc = (const float*)d_in[7];
  float* out = (float*)d_out;

  char* ws = (char*)d_ws;
  // layout: Whb [0,8M) | Wxb [8M,16M) | biasc @16M (16K)
  //         hb0 @16M+64K (512K) | hb1 @+512K | bar @17M+64K (4K)
  __hip_bfloat16* Whb   = (__hip_bfloat16*)(ws);
  __hip_bfloat16* Wxb   = (__hip_bfloat16*)(ws + (8u << 20));
  float*          biasc = (float*)(ws + (16u << 20));
  __hip_bfloat16* hb0   = (__hip_bfloat16*)(ws + (16u << 20) + (1u << 16));
  __hip_bfloat16* hb1   = (__hip_bfloat16*)(ws + (16u << 20) + (1u << 16) + (1u << 19));
  unsigned*       bar   = (unsigned*)(ws + (17u << 20) + (1u << 16));

  hipMemsetAsync(hb0, 0, (size_t)BATCH * HDIM * sizeof(__hip_bfloat16), stream);
  hipMemsetAsync(bar, 0, 4096, stream);

  pack_kernel<<<1024, 256, 0, stream>>>(Wh, Wx, bx, bh, Whb, Wxb, biasc);

  {
    const float* xa = x;
    const __hip_bfloat16* wha = Whb;
    const __hip_bfloat16* wxa = Wxb;
    const float* ba = biasc;
    const float* ca = c2c;
    __hip_bfloat16* h0a = hb0;
    __hip_bfloat16* h1a = hb1;
    unsigned* bara = bar;
    void* args[] = { (void*)&xa, (void*)&wha, (void*)&wxa, (void*)&ba,
                     (void*)&ca, (void*)&h0a, (void*)&h1a, (void*)&bara };
    hipLaunchCooperativeKernel((const void*)lstm_persist, dim3(256), dim3(512),
                               args, 0, stream);
  }

  fc_kernel<<<64, 256, 0, stream>>>(hb0, Wfc, bfc, out);
}

// Round 5
// 15231.786 us; speedup vs baseline: 1.3068x; 1.3068x over previous
//
#include <hip/hip_runtime.h>
#include <hip/hip_bf16.h>
#include <stdint.h>

typedef __attribute__((ext_vector_type(8))) short short8;
typedef __attribute__((ext_vector_type(4))) float f32x4;

#define T_STEPS 512
#define BATCH   256
#define HDIM    1024
#define GDIM    4096   // 4*H

__device__ __forceinline__ float sigmoidf_(float v) {
  return 1.0f / (1.0f + __expf(-v));
}
__device__ __forceinline__ float tanh_(float v) {
  return 2.0f / (1.0f + __expf(-2.0f * v)) - 1.0f;
}
__device__ __forceinline__ short f2bf(float f) {
  __hip_bfloat16 h = __float2bfloat16(f);
  short s;
  __builtin_memcpy(&s, &h, 2);
  return s;
}

// ---------------------------------------------------------------------------
// Pack: Whb=bf16(Wh), Wxb=bf16(Wx) [4096][1024]; biasc = bx + bh
// ---------------------------------------------------------------------------
__global__ void pack_kernel(const float* __restrict__ Wh, const float* __restrict__ Wx,
                            const float* __restrict__ bx, const float* __restrict__ bh,
                            __hip_bfloat16* __restrict__ Whb,
                            __hip_bfloat16* __restrict__ Wxb,
                            float* __restrict__ biasc)
{
  const int stride = gridDim.x * blockDim.x;
  const int tid0 = blockIdx.x * blockDim.x + threadIdx.x;
  for (int i = tid0; i < GDIM * HDIM; i += stride) {
    Whb[i] = __float2bfloat16(Wh[i]);
    Wxb[i] = __float2bfloat16(Wx[i]);
  }
  for (int i = tid0; i < GDIM; i += stride)
    biasc[i] = bx[i] + bh[i];
}

// LDS partial-sum index with bank skew:
// layout [wh(2)][ks(4)][rr(32)][c(64)] f32; skew keeps writes 2-lane/bank and
// reads at the b64 floor.
#define RIDX(BASE, KS, RR, CC)                                                \
  ((BASE) + (KS) * 2048 + (RR) * 64 +                                         \
   ((((CC) + ((((RR) >> 2) & 3) << 4) + (((RR) & 3) << 1))) & 63))

// coherent (MALL) 16B load: SGPR base + 32-bit VGPR byte offset + literal imm
#define HL(dst, off, base, LIT)                                               \
  asm volatile("global_load_dwordx4 %0, %1, %2 offset:" LIT " sc0 sc1"        \
               : "=v"(dst) : "v"(off), "s"(base) : "memory")

// ---------------------------------------------------------------------------
// Persistent LSTM, all 512 steps, one cooperative launch.
// 256 blocks (1/CU) x 512 thr. Block tile: 64 batch x (16 j x 4 gates).
// 4 independent groups (batch slices); grid barrier = 64 blocks/group.
// Waves: (wh 0..1 row-half) x (ks 0..3 k-slice of 256). Wh fragments live in
// REGISTERS (bw[4][8], 128 VGPR, loaded once). h crosses steps via sc0/sc1
// (MALL-coherent) loads/stores; NO fences -> L2 stays warm for x/Wxb.
// ---------------------------------------------------------------------------
__global__ __launch_bounds__(512, 1)
void lstm_persist(const float* __restrict__ x,
                  const __hip_bfloat16* __restrict__ Whb,
                  const __hip_bfloat16* __restrict__ Wxb,
                  const float* __restrict__ biasc,
                  const float* __restrict__ c2c,
                  __hip_bfloat16* __restrict__ hb0,
                  __hip_bfloat16* __restrict__ hb1,
                  unsigned* __restrict__ bar)
{
  __shared__ float red[32768];   // [0,16K): gate partials; [16K,32K): xg partials

  const int tid  = threadIdx.x;
  const int wave = tid >> 6;
  const int lane = tid & 63;
  const int l15  = lane & 15;
  const int lg   = lane >> 4;

  const int bid   = blockIdx.x;
  const int grp   = (bid & 7) >> 1;           // batch-slice group (XCD pair)
  const int half  = bid & 1;
  const int ntile = half * 32 + (bid >> 3);   // 0..63
  const int b0    = grp * 64;
  const int j0    = ntile * 16;

  const int wh = wave & 1;    // row half (32 rows)
  const int ks = wave >> 1;   // k-slice (256 k)

  // ---- persistent Wh fragments in registers: bw[gate][kc] ----
  short8 bw[4][8];
#pragma unroll
  for (int n = 0; n < 4; ++n) {
    const __hip_bfloat16* wp = Whb + (size_t)(n * 1024 + j0 + l15) * HDIM + ks * 256 + lg * 8;
#pragma unroll
    for (int kc = 0; kc < 8; ++kc)
      bw[n][kc] = *(const short8*)(const void*)(wp + kc * 32);
  }
  float biasw[4];
#pragma unroll
  for (int n = 0; n < 4; ++n) biasw[n] = biasc[n * 1024 + j0 + l15];

  // ---- phase-A h addresses: uniform base (SGPR) + 32-bit lane offset ----
  const unsigned aoff0 = (unsigned)(((b0 + wh * 32 + l15) * HDIM + ks * 256 + lg * 8) * 2);
  const unsigned aoff1 = aoff0 + 16 * HDIM * 2;
  const uint64_t hB0 = (uint64_t)hb0, hB1 = (uint64_t)hb1;

  // ---- phase-B sources ----
  const float* xp0base = x + (size_t)(b0 + wh * 32 + l15) * T_STEPS * 1024 + ks * 256 + lg * 8;
  const __hip_bfloat16* wxbase = Wxb + (size_t)(j0 + l15) * HDIM + ks * 256 + lg * 8;

  // ---- epilogue thread mapping: thread owns cells (rt, c0), (rt, c0+1) ----
  const int rt = tid >> 3, jp = tid & 7;
  const int ewh = rt >> 5, err = rt & 31;
  const int c0 = jp * 2, jj = j0 + c0;
  const float ci0 = c2c[jj],            ci1 = c2c[jj + 1];
  const float cf0 = c2c[HDIM + jj],     cf1 = c2c[HDIM + jj + 1];
  const float co0 = c2c[2 * HDIM + jj], co1 = c2c[2 * HDIM + jj + 1];
  const unsigned soff = (unsigned)(((b0 + rt) * HDIM + jj) * 2);
  float cc0 = 0.f, cc1 = 0.f;

  unsigned* cntH = bar + (size_t)(grp * 2 + half) * 32;
  unsigned* cnt2 = bar + (size_t)(8 + grp) * 32;
  unsigned* genp = bar + (size_t)(12 + grp) * 32;

  // ---- phase B: xg(TN) partials (with bias folded into ks==0) -> red2 ----
#define PHASE_B(TN)                                                            \
  do {                                                                         \
    f32x4 accx[2][4];                                                          \
    _Pragma("unroll") for (int m_ = 0; m_ < 2; ++m_)                           \
      _Pragma("unroll") for (int n_ = 0; n_ < 4; ++n_)                         \
        accx[m_][n_] = (f32x4){0.f, 0.f, 0.f, 0.f};                            \
    const float* xq0 = xp0base + (size_t)(TN) * 1024;                          \
    const float* xq1 = xq0 + (size_t)16 * T_STEPS * 1024;                      \
    f32x4 xbl[2][2], xbh[2][2]; short8 wv[2][4];                               \
    xbl[0][0] = *(const f32x4*)(xq0);  xbh[0][0] = *(const f32x4*)(xq0 + 4);   \
    xbl[0][1] = *(const f32x4*)(xq1);  xbh[0][1] = *(const f32x4*)(xq1 + 4);   \
    _Pragma("unroll") for (int n_ = 0; n_ < 4; ++n_)                           \
      wv[0][n_] = *(const short8*)(const void*)(wxbase + (size_t)n_ * 1048576);\
    _Pragma("unroll")                                                          \
    for (int kc = 0; kc < 8; ++kc) {                                           \
      const int cur = kc & 1, nxt = cur ^ 1;                                   \
      if (kc < 7) {                                                            \
        xbl[nxt][0] = *(const f32x4*)(xq0 + (kc + 1) * 32);                    \
        xbh[nxt][0] = *(const f32x4*)(xq0 + (kc + 1) * 32 + 4);                \
        xbl[nxt][1] = *(const f32x4*)(xq1 + (kc + 1) * 32);                    \
        xbh[nxt][1] = *(const f32x4*)(xq1 + (kc + 1) * 32 + 4);                \
        _Pragma("unroll") for (int n_ = 0; n_ < 4; ++n_)                       \
          wv[nxt][n_] = *(const short8*)(const void*)                          \
              (wxbase + (size_t)n_ * 1048576 + (kc + 1) * 32);                 \
      }                                                                        \
      short8 xa0, xa1;                                                         \
      _Pragma("unroll") for (int e = 0; e < 4; ++e) {                          \
        xa0[e] = f2bf(xbl[cur][0][e]); xa0[e + 4] = f2bf(xbh[cur][0][e]);      \
        xa1[e] = f2bf(xbl[cur][1][e]); xa1[e + 4] = f2bf(xbh[cur][1][e]);      \
      }                                                                        \
      _Pragma("unroll") for (int n_ = 0; n_ < 4; ++n_) {                       \
        accx[0][n_] = __builtin_amdgcn_mfma_f32_16x16x32_bf16(                 \
            xa0, wv[cur][n_], accx[0][n_], 0, 0, 0);                           \
        accx[1][n_] = __builtin_amdgcn_mfma_f32_16x16x32_bf16(                 \
            xa1, wv[cur][n_], accx[1][n_], 0, 0, 0);                           \
      }                                                                        \
    }                                                                          \
    _Pragma("unroll") for (int m_ = 0; m_ < 2; ++m_)                           \
      _Pragma("unroll") for (int n_ = 0; n_ < 4; ++n_) {                       \
        const float badd = (ks == 0) ? biasw[n_] : 0.0f;                       \
        _Pragma("unroll") for (int r_ = 0; r_ < 4; ++r_)                       \
          red[RIDX(16384 + wh * 8192, ks, m_ * 16 + lg * 4 + r_,               \
                   n_ * 16 + l15)] = accx[m_][n_][r_] + badd;                  \
      }                                                                        \
  } while (0)

  PHASE_B(0);
  __syncthreads();

#pragma unroll 1
  for (int s = 0; s < T_STEPS; ++s) {
    // ---- phase A: coherent h loads -> MFMA from registers ----
    const uint64_t hbase = (s & 1) ? hB1 : hB0;
    short8 hv0[8], hv1[8];
    HL(hv0[0], aoff0, hbase, "0");   HL(hv0[1], aoff0, hbase, "64");
    HL(hv0[2], aoff0, hbase, "128"); HL(hv0[3], aoff0, hbase, "192");
    HL(hv0[4], aoff0, hbase, "256"); HL(hv0[5], aoff0, hbase, "320");
    HL(hv0[6], aoff0, hbase, "384"); HL(hv0[7], aoff0, hbase, "448");
    HL(hv1[0], aoff1, hbase, "0");   HL(hv1[1], aoff1, hbase, "64");
    HL(hv1[2], aoff1, hbase, "128"); HL(hv1[3], aoff1, hbase, "192");
    HL(hv1[4], aoff1, hbase, "256"); HL(hv1[5], aoff1, hbase, "320");
    HL(hv1[6], aoff1, hbase, "384"); HL(hv1[7], aoff1, hbase, "448");
    asm volatile("s_waitcnt vmcnt(0)" ::: "memory");
    __builtin_amdgcn_sched_barrier(0);

    f32x4 acc[2][4];
#pragma unroll
    for (int m = 0; m < 2; ++m)
#pragma unroll
      for (int n = 0; n < 4; ++n) acc[m][n] = (f32x4){0.f, 0.f, 0.f, 0.f};

#pragma unroll
    for (int kc = 0; kc < 8; ++kc) {
#pragma unroll
      for (int n = 0; n < 4; ++n) {
        acc[0][n] = __builtin_amdgcn_mfma_f32_16x16x32_bf16(hv0[kc], bw[n][kc], acc[0][n], 0, 0, 0);
        acc[1][n] = __builtin_amdgcn_mfma_f32_16x16x32_bf16(hv1[kc], bw[n][kc], acc[1][n], 0, 0, 0);
      }
    }

    // ---- write gate partials ----
#pragma unroll
    for (int m = 0; m < 2; ++m)
#pragma unroll
      for (int n = 0; n < 4; ++n)
#pragma unroll
        for (int r = 0; r < 4; ++r)
          red[RIDX(wh * 8192, ks, m * 16 + lg * 4 + r, n * 16 + l15)] = acc[m][n][r];

    __syncthreads();

    // ---- epilogue: gather 4 k-slices of (gates, xg), run the cell ----
    float g0[4], g1[4];
#pragma unroll
    for (int g = 0; g < 4; ++g) {
      float s0 = 0.f, s1 = 0.f;
#pragma unroll
      for (int kq = 0; kq < 4; ++kq) {
        const float* pa = &red[RIDX(ewh * 8192, kq, err, g * 16 + c0)];
        const float* pb = &red[RIDX(16384 + ewh * 8192, kq, err, g * 16 + c0)];
        s0 += pa[0] + pb[0];
        s1 += pa[1] + pb[1];
      }
      g0[g] = s0; g1[g] = s1;
    }
    {
      float ii = sigmoidf_(g0[0] + ci0 * cc0);
      float ff = sigmoidf_(g0[1] + cf0 * cc0);
      float gg = tanh_(g0[2]);
      float cn = ff * cc0 + ii * gg;
      float oo = sigmoidf_(g0[3] + co0 * cn);
      float hh0 = oo * tanh_(cn);
      cc0 = cn;
      ii = sigmoidf_(g1[0] + ci1 * cc1);
      ff = sigmoidf_(g1[1] + cf1 * cc1);
      gg = tanh_(g1[2]);
      cn = ff * cc1 + ii * gg;
      oo = sigmoidf_(g1[3] + co1 * cn);
      float hh1 = oo * tanh_(cn);
      cc1 = cn;
      unsigned pk = (unsigned)(unsigned short)f2bf(hh0) |
                    ((unsigned)(unsigned short)f2bf(hh1) << 16);
      const uint64_t sbase = (s & 1) ? hB0 : hB1;
      asm volatile("global_store_dword %0, %1, %2 sc0 sc1"
                   :: "v"(soff), "v"(pk), "s"(sbase) : "memory");
    }
    asm volatile("s_waitcnt vmcnt(0)" ::: "memory");   // h visible at MALL
    __syncthreads();

    if (s == T_STEPS - 1) break;

    // ---- arrive (relaxed system atomics; monotonic counters) ----
    if (tid == 0) {
      unsigned a = __hip_atomic_fetch_add(cntH, 1u, __ATOMIC_RELAXED, __HIP_MEMORY_SCOPE_SYSTEM);
      if ((a & 31u) == 31u) {
        unsigned b2 = __hip_atomic_fetch_add(cnt2, 1u, __ATOMIC_RELAXED, __HIP_MEMORY_SCOPE_SYSTEM);
        if (b2 & 1u)
          __hip_atomic_fetch_add(genp, 1u, __ATOMIC_RELAXED, __HIP_MEMORY_SCOPE_SYSTEM);
      }
    }

    PHASE_B(s + 1);   // overlaps barrier settle; writes red2 (+bias)

    if (tid == 0) {
      while (__hip_atomic_load(genp, __ATOMIC_RELAXED, __HIP_MEMORY_SCOPE_SYSTEM) <= (unsigned)s)
        __builtin_amdgcn_s_sleep(1);
    }
    __syncthreads();
  }
#undef PHASE_B
}

// ---------------------------------------------------------------------------
// Final FC: out[b][o] = h[b][:] . Wfc[o][:] + bfc[o]  (M=256,N=1024,K=1024)
// ---------------------------------------------------------------------------
__global__ __launch_bounds__(256, 1)
void fc_kernel(const __hip_bfloat16* __restrict__ h,
               const float* __restrict__ Wfc,
               const float* __restrict__ bfc,
               float* __restrict__ out)
{
  __shared__ short8 As8[512];
  __shared__ short8 Bs8[512];

  const int tid = threadIdx.x;
  const int wave = tid >> 6;
  const int lane = tid & 63;
  const int mtile = blockIdx.x >> 4;
  const int otile = blockIdx.x & 15;
  const int b0 = mtile * 64, o0 = otile * 64;

  const int r0 = tid >> 3;
  const int cg0 = tid & 7;

  f32x4 acc[4];
#pragma unroll
  for (int f = 0; f < 4; ++f) acc[f] = (f32x4){0.f, 0.f, 0.f, 0.f};

#pragma unroll 1
  for (int kc = 0; kc < 16; ++kc) {
    __syncthreads();
    As8[r0 * 8 + (cg0 ^ (r0 & 7))] =
        *(const short8*)(const void*)(h + (size_t)(b0 + r0) * HDIM + kc * 64 + cg0 * 8);
    As8[(r0 + 32) * 8 + (cg0 ^ (r0 & 7))] =
        *(const short8*)(const void*)(h + (size_t)(b0 + r0 + 32) * HDIM + kc * 64 + cg0 * 8);
    {
      const float* p0 = Wfc + (size_t)(o0 + r0) * HDIM + kc * 64 + cg0 * 8;
      const float* p1 = Wfc + (size_t)(o0 + r0 + 32) * HDIM + kc * 64 + cg0 * 8;
      f32x4 l0 = *(const f32x4*)p0, h0 = *(const f32x4*)(p0 + 4);
      f32x4 l1 = *(const f32x4*)p1, h1 = *(const f32x4*)(p1 + 4);
      short8 s0, s1;
#pragma unroll
      for (int e = 0; e < 4; ++e) {
        s0[e] = f2bf(l0[e]); s0[e + 4] = f2bf(h0[e]);
        s1[e] = f2bf(l1[e]); s1[e + 4] = f2bf(h1[e]);
      }
      Bs8[r0 * 8 + (cg0 ^ (r0 & 7))] = s0;
      Bs8[(r0 + 32) * 8 + (cg0 ^ (r0 & 7))] = s1;
    }
    __syncthreads();
#pragma unroll
    for (int s = 0; s < 2; ++s) {
      const int colg = s * 4 + (lane >> 4);
      const int ar = wave * 16 + (lane & 15);
      short8 af = As8[ar * 8 + (colg ^ (ar & 7))];
#pragma unroll
      for (int f = 0; f < 4; ++f) {
        const int br = f * 16 + (lane & 15);
        short8 bfq = Bs8[br * 8 + (colg ^ (br & 7))];
        acc[f] = __builtin_amdgcn_mfma_f32_16x16x32_bf16(af, bfq, acc[f], 0, 0, 0);
      }
    }
  }

  const int dcol = lane & 15;
  const int drow = (lane >> 4) * 4;
#pragma unroll
  for (int f = 0; f < 4; ++f) {
    const int o = o0 + f * 16 + dcol;
    const float bias = bfc[o];
#pragma unroll
    for (int r = 0; r < 4; ++r) {
      const int b = b0 + wave * 16 + drow + r;
      out[(size_t)b * 1024 + o] = acc[f][r] + bias;
    }
  }
}

// ---------------------------------------------------------------------------
extern "C" void kernel_launch(void* const* d_in, const int* in_sizes, int n_in,
                              void* d_out, int out_size, void* d_ws, size_t ws_size,
                              hipStream_t stream)
{
  const float* x   = (const float*)d_in[0];
  const float* Wx  = (const float*)d_in[1];
  const float* bx  = (const float*)d_in[2];
  const float* Wh  = (const float*)d_in[3];
  const float* bh  = (const float*)d_in[4];
  const float* c2c = (const float*)d_in[5];
  const float* Wfc = (const float*)d_in[6];
  const float* bfc = (const float*)d_in[7];
  float* out = (float*)d_out;

  char* ws = (char*)d_ws;
  // layout: Whb [0,8M) | Wxb [8M,16M) | biasc @16M (16K)
  //         hb0 @16M+64K (512K) | hb1 +512K | bar @17M+64K (4K)
  __hip_bfloat16* Whb   = (__hip_bfloat16*)(ws);
  __hip_bfloat16* Wxb   = (__hip_bfloat16*)(ws + (8u << 20));
  float*          biasc = (float*)(ws + (16u << 20));
  __hip_bfloat16* hb0   = (__hip_bfloat16*)(ws + (16u << 20) + (1u << 16));
  __hip_bfloat16* hb1   = (__hip_bfloat16*)(ws + (16u << 20) + (1u << 16) + (1u << 19));
  unsigned*       bar   = (unsigned*)(ws + (17u << 20) + (1u << 16));

  hipMemsetAsync(hb0, 0, (size_t)BATCH * HDIM * sizeof(__hip_bfloat16), stream);
  hipMemsetAsync(bar, 0, 4096, stream);

  pack_kernel<<<1024, 256, 0, stream>>>(Wh, Wx, bx, bh, Whb, Wxb, biasc);

  {
    const float* xa = x;
    const __hip_bfloat16* wha = Whb;
    const __hip_bfloat16* wxa = Wxb;
    const float* ba = biasc;
    const float* ca = c2c;
    __hip_bfloat16* h0a = hb0;
    __hip_bfloat16* h1a = hb1;
    unsigned* bara = bar;
    void* args[] = { (void*)&xa, (void*)&wha, (void*)&wxa, (void*)&ba,
                     (void*)&ca, (void*)&h0a, (void*)&h1a, (void*)&bara };
    hipLaunchCooperativeKernel((const void*)lstm_persist, dim3(256), dim3(512),
                               args, 0, stream);
  }

  fc_kernel<<<64, 256, 0, stream>>>(hb0, Wfc, bfc, out);
}